// Round 5
// baseline (193.986 us; speedup 1.0000x reference)
//
#include <hip/hip_runtime.h>
#include <hip/hip_bf16.h>
#include <stdint.h>

#define HEADS 16
#define DH    64
#define SEQ   1024
#define DIM   1024

typedef __attribute__((ext_vector_type(8))) short bf16x8;
typedef __attribute__((ext_vector_type(4))) float f32x4;
typedef __attribute__((ext_vector_type(16))) float f32x16;
typedef __attribute__((ext_vector_type(4))) unsigned int u32x4;

// 0.125 * log2(e): folded into Q at GEMM epilogue so softmax uses exp2 directly
#define QSCALE_L2 0.18033688011112042f
// 8 nats in log2 units (defer-max threshold, T13)
#define THR_L2 11.541560327111707f
#define PEN_L2 (-14427.0f)   // -10000 * log2(e)

static __device__ __forceinline__ unsigned short f2bf(float f) {
  unsigned u = __builtin_bit_cast(unsigned, f);
  u += 0x7fff + ((u >> 16) & 1);   // RNE
  return (unsigned short)(u >> 16);
}

static __device__ __forceinline__ float fexp2(float x) {
#if __has_builtin(__builtin_amdgcn_exp2f)
  return __builtin_amdgcn_exp2f(x);
#else
  return exp2f(x);
#endif
}

static __device__ __forceinline__ void gload_lds16(const void* g, void* l) {
  __builtin_amdgcn_global_load_lds(
      (const __attribute__((address_space(1))) unsigned int*)g,
      (__attribute__((address_space(3))) unsigned int*)l,
      16, 0, 0);
}

// ---------------- Kernel B: keep-list scan per batch -------------------------
// inv[b][n] = compact index (or -1 if masked out); penc[b][i] = 0 / -14427 bf16
__global__ __launch_bounds__(256) void build_keep(
    const int* __restrict__ mask, int* __restrict__ inv,
    unsigned short* __restrict__ penc, int* __restrict__ nkeep) {
  const int b = blockIdx.x;
  const int t = threadIdx.x;
  __shared__ int sc[256];
  int kept[4];
  int c = 0;
#pragma unroll
  for (int k = 0; k < 4; ++k) {
    const int j = t * 4 + k;
    const int kp = (j == 0) ? 1 : (mask[b * (SEQ - 1) + j - 1] != 0);
    kept[k] = kp;
    c += kp;
  }
  sc[t] = c;
  __syncthreads();
  for (int off = 1; off < 256; off <<= 1) {
    const int v = (t >= off) ? sc[t - off] : 0;
    __syncthreads();
    sc[t] += v;
    __syncthreads();
  }
  int pos = sc[t] - c;          // exclusive prefix
  const int total = sc[255];
#pragma unroll
  for (int k = 0; k < 4; ++k) {
    const int j = t * 4 + k;
    if (kept[k]) {
      inv[b * SEQ + j] = pos++;
    } else {
      inv[b * SEQ + j] = -1;
    }
  }
#pragma unroll
  for (int k = 0; k < 4; ++k) {
    const int i = t * 4 + k;
    penc[b * SEQ + i] = (i < total) ? (unsigned short)0 : f2bf(PEN_L2);
  }
  if (t == 0) nkeep[b] = total;
}

// ---------------- Kernel A: x f32 -> bf16 -----------------------------------
__global__ __launch_bounds__(256) void cvt_x(
    const float* __restrict__ in, unsigned short* __restrict__ out) {
  const int i = (blockIdx.x * 256 + threadIdx.x) * 4;
  const float4 v = *reinterpret_cast<const float4*>(in + i);
  short4 o;
  o.x = (short)f2bf(v.x);
  o.y = (short)f2bf(v.y);
  o.z = (short)f2bf(v.z);
  o.w = (short)f2bf(v.w);
  *reinterpret_cast<short4*>(out + i) = o;
}

// ---------------- Kernel 0: w f32 [1024][3072] -> wT bf16 [3072][1024] ------
__global__ __launch_bounds__(256) void transpose_w(
    const float* __restrict__ w, unsigned short* __restrict__ wT) {
  __shared__ unsigned short t[64][68];
  const int tid = threadIdx.x;
  const int bk = blockIdx.x;
  const int bn = blockIdx.y;
  const int r = tid >> 4;
  const int c = (tid & 15) * 4;
#pragma unroll
  for (int rr = 0; rr < 64; rr += 16) {
    const float4 v = *reinterpret_cast<const float4*>(
        w + (size_t)(bk * 64 + r + rr) * 3072 + bn * 64 + c);
    t[r + rr][c + 0] = f2bf(v.x);
    t[r + rr][c + 1] = f2bf(v.y);
    t[r + rr][c + 2] = f2bf(v.z);
    t[r + rr][c + 3] = f2bf(v.w);
  }
  __syncthreads();
#pragma unroll
  for (int rr = 0; rr < 64; rr += 16) {
    short4 o;
    o.x = (short)t[c + 0][r + rr];
    o.y = (short)t[c + 1][r + rr];
    o.z = (short)t[c + 2][r + rr];
    o.w = (short)t[c + 3][r + rr];
    *reinterpret_cast<short4*>(
        wT + (size_t)(bn * 64 + r + rr) * 1024 + bk * 64 + c) = o;
  }
}

// ---------------- Kernel 1: qkv = x @ w, scattered to Qh/Kc/Vtc -------------
// Qh: [b,h,n,64] PRE-SCALED by 0.125*log2e ; Kc: [b,h,i,64]; Vtc: [b,h,64,i]
// K/V rows are written at COMPACT position inv[b][n] (skipped if masked out).
// N-tile is 128-wide and 128 | 1024, so each block's columns live in ONE
// section (q/k/v): sec = n0>>10 is block-uniform -> specialized epilogues.
__global__ __launch_bounds__(256) void qkv_gemm(
    const unsigned short* __restrict__ x, const unsigned short* __restrict__ wT,
    const int* __restrict__ inv,
    unsigned short* __restrict__ Qh, unsigned short* __restrict__ Kc,
    unsigned short* __restrict__ Vtc) {
  __shared__ unsigned short Al[128 * 32];
  __shared__ unsigned short Bl[128 * 32];
  const int tid = threadIdx.x;
  const int lane = tid & 63;
  const int wave = tid >> 6;
  // T1: XCD-aware bijective swizzle over 1536 blocks (1536 % 8 == 0)
  const int lin = blockIdx.x;
  const int swz = (lin & 7) * 192 + (lin >> 3);
  const int m0 = (swz & 63) * 128;       // 64 M-tiles
  const int n0 = (swz >> 6) * 128;       // 24 N-tiles
  const int wm = (wave >> 1) * 64;
  const int wn = (wave & 1) * 64;
  const int l15 = lane & 15;
  const int kb8 = (lane >> 4) * 8;

  f32x4 acc[4][4] = {};

  for (int kt = 0; kt < DIM; kt += 32) {
    __syncthreads();
#pragma unroll
    for (int rnd = 0; rnd < 2; ++rnd) {
      const int off = tid * 16 + rnd * 4096;
      const int row = off >> 6;
      const int kc = (off & 63) >> 1;
      gload_lds16(x + (size_t)(m0 + row) * DIM + kt + kc, (char*)Al + off);
      gload_lds16(wT + (size_t)(n0 + row) * DIM + kt + kc, (char*)Bl + off);
    }
    __syncthreads();
    bf16x8 af[4], bfr[4];
#pragma unroll
    for (int i = 0; i < 4; ++i)
      af[i] = *reinterpret_cast<const bf16x8*>(&Al[(wm + i * 16 + l15) * 32 + kb8]);
#pragma unroll
    for (int j = 0; j < 4; ++j)
      bfr[j] = *reinterpret_cast<const bf16x8*>(&Bl[(wn + j * 16 + l15) * 32 + kb8]);
#pragma unroll
    for (int i = 0; i < 4; ++i)
#pragma unroll
      for (int j = 0; j < 4; ++j)
        acc[i][j] = __builtin_amdgcn_mfma_f32_16x16x32_bf16(af[i], bfr[j], acc[i][j], 0, 0, 0);
  }

  const int sec = n0 >> 10;              // block-uniform: 0=q 1=k 2=v
  if (sec == 0) {
#pragma unroll
    for (int i = 0; i < 4; ++i) {
#pragma unroll
      for (int j = 0; j < 4; ++j) {
        const int col = n0 + wn + j * 16 + l15;
        const int h = (col >> 6) & 15;
        const int dh = col & 63;
#pragma unroll
        for (int r = 0; r < 4; ++r) {
          const int rowg = m0 + wm + i * 16 + (lane >> 4) * 4 + r;
          const int b = rowg >> 10;
          const int n = rowg & 1023;
          Qh[(((size_t)b * HEADS + h) * SEQ + n) * DH + dh] =
              f2bf(acc[i][j][r] * QSCALE_L2);
        }
      }
    }
  } else {
    int ivr[4][4];
#pragma unroll
    for (int i = 0; i < 4; ++i)
#pragma unroll
      for (int r = 0; r < 4; ++r) {
        const int rowg = m0 + wm + i * 16 + (lane >> 4) * 4 + r;
        ivr[i][r] = inv[(rowg >> 10) * SEQ + (rowg & 1023)];
      }
    if (sec == 1) {
#pragma unroll
      for (int i = 0; i < 4; ++i) {
#pragma unroll
        for (int j = 0; j < 4; ++j) {
          const int col = n0 + wn + j * 16 + l15;
          const int h = (col >> 6) & 15;
          const int dh = col & 63;
#pragma unroll
          for (int r = 0; r < 4; ++r) {
            const int rowg = m0 + wm + i * 16 + (lane >> 4) * 4 + r;
            const int b = rowg >> 10;
            const int iv = ivr[i][r];
            if (iv >= 0)
              Kc[(((size_t)b * HEADS + h) * SEQ + iv) * DH + dh] =
                  f2bf(acc[i][j][r]);
          }
        }
      }
    } else {
#pragma unroll
      for (int i = 0; i < 4; ++i) {
#pragma unroll
        for (int j = 0; j < 4; ++j) {
          const int col = n0 + wn + j * 16 + l15;
          const int h = (col >> 6) & 15;
          const int dh = col & 63;
#pragma unroll
          for (int r = 0; r < 4; ++r) {
            const int rowg = m0 + wm + i * 16 + (lane >> 4) * 4 + r;
            const int b = rowg >> 10;
            const int iv = ivr[i][r];
            if (iv >= 0)
              Vtc[(((size_t)b * HEADS + h) * DH + dh) * SEQ + iv] =
                  f2bf(acc[i][j][r]);
          }
        }
      }
    }
  }
}

// ---------------- Kernel 2: flash attention over compacted KV ---------------
// block = 4 waves x 32 q-rows of one (b,h); 32x32x16 MFMA; K-frag double buffer.
__global__ __launch_bounds__(256) void attn_fwd3(
    const unsigned short* __restrict__ Qh, const unsigned short* __restrict__ Kc,
    const unsigned short* __restrict__ Vtc, const unsigned short* __restrict__ penc,
    const int* __restrict__ nkeep, float* __restrict__ out) {
  __shared__ unsigned short penb[SEQ];
  __shared__ float corrw[4][32];
  const int tid = threadIdx.x;
  const int lane = tid & 63;
  const int wave = tid >> 6;
  const int l31 = lane & 31;
  const int h8 = (lane >> 5) * 8;
  const bool islo = lane < 32;

  // XCD swizzle: 128 consecutive logical blocks (16 heads) per XCD
  const int bid = ((blockIdx.x & 7) << 7) | (blockIdx.x >> 3);
  const int b = bid >> 7;
  const int hh = (bid >> 3) & 15;
  const int qc = bid & 7;
  const size_t bh = (size_t)b * HEADS + hh;
  const int q0 = qc * 128 + wave * 32;

  const int nk = nkeep[b];
  const int nt64 = (nk + 63) & ~63;

  for (int j = tid; j < SEQ; j += 256) penb[j] = penc[b * SEQ + j];
  __syncthreads();

  const unsigned short* Q = Qh + bh * SEQ * DH;
  const unsigned short* K = Kc + bh * SEQ * DH;
  const unsigned short* V = Vtc + bh * DH * SEQ;   // [64][1024] compacted cols

  bf16x8 qf[4];
#pragma unroll
  for (int ds = 0; ds < 4; ++ds)
    qf[ds] = *reinterpret_cast<const bf16x8*>(
        Q + (size_t)(q0 + l31) * DH + ds * 16 + h8);

  u32x4 onesu = {0u, 0u, 0u, 0u};
  onesu.x = islo ? 0x3F80u : 0u;     // bf16 1.0 at k==0 of lane-half 0
  const bf16x8 onesf = __builtin_bit_cast(bf16x8, onesu);

  f32x16 Od0 = (f32x16)0.f, Od1 = (f32x16)0.f;
  float m_ = 0.f, l_ = 0.f;

  bf16x8 kfA[8], kfB[8];
  auto loadK = [&](bf16x8* dst, int ktt) {
#pragma unroll
    for (int ds = 0; ds < 4; ++ds) {
      dst[ds]     = *reinterpret_cast<const bf16x8*>(
          K + (size_t)(ktt + l31) * DH + ds * 16 + h8);
      dst[ds + 4] = *reinterpret_cast<const bf16x8*>(
          K + (size_t)(ktt + 32 + l31) * DH + ds * 16 + h8);
    }
  };
  loadK(kfA, 0);

  auto step = [&](const bf16x8* kc, bf16x8* kn, int kt) {
    // V frags issued first: latency hides under QK^T + softmax
    bf16x8 vf[8];
#pragma unroll
    for (int dt = 0; dt < 2; ++dt)
#pragma unroll
      for (int kvs = 0; kvs < 4; ++kvs)
        vf[dt * 4 + kvs] = *reinterpret_cast<const bf16x8*>(
            V + (size_t)(dt * 32 + l31) * SEQ + kt + kvs * 16 + h8);
    // S^T = K·Q^T (log2 units)
    f32x16 st0 = (f32x16)0.f, st1 = (f32x16)0.f;
    __builtin_amdgcn_s_setprio(1);
#pragma unroll
    for (int ds = 0; ds < 4; ++ds) {
      st0 = __builtin_amdgcn_mfma_f32_32x32x16_bf16(kc[ds], qf[ds], st0, 0, 0, 0);
      st1 = __builtin_amdgcn_mfma_f32_32x32x16_bf16(kc[ds + 4], qf[ds], st1, 0, 0, 0);
    }
    __builtin_amdgcn_s_setprio(0);
    // prefetch next K tile (clamped; hides under softmax+pack+PV)
    const int ktn = (kt + 64 < nt64) ? kt + 64 : 0;
    loadK(kn, ktn);
    // tail mask via rank-1 MFMA: st[kv][q] += penb[kv]
    {
      const unsigned short pu0 = penb[kt + l31];
      const unsigned short pu1 = penb[kt + 32 + l31];
      u32x4 p0 = {0u, 0u, 0u, 0u}, p1 = {0u, 0u, 0u, 0u};
      p0.x = islo ? (unsigned)pu0 : 0u;
      p1.x = islo ? (unsigned)pu1 : 0u;
      st0 = __builtin_amdgcn_mfma_f32_32x32x16_bf16(
          __builtin_bit_cast(bf16x8, p0), onesf, st0, 0, 0, 0);
      st1 = __builtin_amdgcn_mfma_f32_32x32x16_bf16(
          __builtin_bit_cast(bf16x8, p1), onesf, st1, 0, 0, 0);
    }
    // row max
    float a[8];
#pragma unroll
    for (int i = 0; i < 8; ++i)
      a[i] = fmaxf(fmaxf(st0[i], st0[i + 8]), fmaxf(st1[i], st1[i + 8]));
#pragma unroll
    for (int k = 4; k >= 1; k >>= 1)
#pragma unroll
      for (int i = 0; i < k; ++i) a[i] = fmaxf(a[i], a[i + k]);
    const float mx = fmaxf(a[0], __shfl_xor(a[0], 32));
    // deferred rescale (rare)
    if (!__all(mx <= m_ + THR_L2)) {
      const float mn = fmaxf(m_, mx);
      const float corr = fexp2(m_ - mn);
      m_ = mn;
      l_ *= corr;
      if (islo) corrw[wave][l31] = corr;
      f32x4 cv[4];
#pragma unroll
      for (int j = 0; j < 4; ++j)
        cv[j] = *reinterpret_cast<const f32x4*>(&corrw[wave][j * 8 + (h8 >> 1)]);
#pragma unroll
      for (int r = 0; r < 16; ++r) {
        Od0[r] *= cv[r >> 2][r & 3];
        Od1[r] *= cv[r >> 2][r & 3];
      }
    }
    // P = exp2(st - m)
#pragma unroll
    for (int i = 0; i < 16; ++i) {
      st0[i] = fexp2(st0[i] - m_);
      st1[i] = fexp2(st1[i] - m_);
    }
    // row sum
    float s8[8];
#pragma unroll
    for (int i = 0; i < 8; ++i)
      s8[i] = (st0[i] + st0[i + 8]) + (st1[i] + st1[i + 8]);
#pragma unroll
    for (int k = 4; k >= 1; k >>= 1)
#pragma unroll
      for (int i = 0; i < k; ++i) s8[i] += s8[i + k];
    l_ += s8[0] + __shfl_xor(s8[0], 32);
    // pack P -> A-frags (cvt_pk + permlane32_swap)
    bf16x8 pf[4];
#pragma unroll
    for (int t = 0; t < 2; ++t) {
#pragma unroll
      for (int bq = 0; bq < 2; ++bq) {
        const int o = 8 * bq;
        float e0 = t ? st1[o + 0] : st0[o + 0], e1 = t ? st1[o + 1] : st0[o + 1];
        float e2 = t ? st1[o + 2] : st0[o + 2], e3 = t ? st1[o + 3] : st0[o + 3];
        float e4 = t ? st1[o + 4] : st0[o + 4], e5 = t ? st1[o + 5] : st0[o + 5];
        float e6 = t ? st1[o + 6] : st0[o + 6], e7 = t ? st1[o + 7] : st0[o + 7];
        unsigned A0, A1, B0, B1;
        asm("v_cvt_pk_bf16_f32 %0, %1, %2" : "=v"(A0) : "v"(e0), "v"(e1));
        asm("v_cvt_pk_bf16_f32 %0, %1, %2" : "=v"(A1) : "v"(e2), "v"(e3));
        asm("v_cvt_pk_bf16_f32 %0, %1, %2" : "=v"(B0) : "v"(e4), "v"(e5));
        asm("v_cvt_pk_bf16_f32 %0, %1, %2" : "=v"(B1) : "v"(e6), "v"(e7));
        asm("v_permlane32_swap_b32 %0, %1\n\ts_nop 1" : "+v"(A0), "+v"(B0));
        asm("v_permlane32_swap_b32 %0, %1\n\ts_nop 1" : "+v"(A1), "+v"(B1));
        u32x4 pk4;
        pk4.x = A0; pk4.y = A1; pk4.z = B0; pk4.w = B1;
        pf[t * 2 + bq] = __builtin_bit_cast(bf16x8, pk4);
      }
    }
    // PV
    __builtin_amdgcn_s_setprio(1);
#pragma unroll
    for (int kvs = 0; kvs < 4; ++kvs) {
      Od0 = __builtin_amdgcn_mfma_f32_32x32x16_bf16(pf[kvs], vf[kvs], Od0, 0, 0, 0);
      Od1 = __builtin_amdgcn_mfma_f32_32x32x16_bf16(pf[kvs], vf[4 + kvs], Od1, 0, 0, 0);
    }
    __builtin_amdgcn_s_setprio(0);
  };

  for (int kt = 0; kt < nt64; kt += 128) {
    step(kfA, kfB, kt);
    if (kt + 64 < nt64) step(kfB, kfA, kt + 64);
  }

  // epilogue: O / l
  if (islo) corrw[wave][l31] = 1.0f / l_;
  f32x4 lv[4];
#pragma unroll
  for (int j = 0; j < 4; ++j)
    lv[j] = *reinterpret_cast<const f32x4*>(&corrw[wave][j * 8 + (h8 >> 1)]);
#pragma unroll
  for (int r = 0; r < 16; ++r) {
    const int q = q0 + (r & 3) + 8 * (r >> 2) + ((lane >> 5) << 2);
    out[((size_t)b * SEQ + q) * (HEADS * DH) + hh * DH + 0 * 32 + l31] =
        Od0[r] * lv[r >> 2][r & 3];
    out[((size_t)b * SEQ + q) * (HEADS * DH) + hh * DH + 1 * 32 + l31] =
        Od1[r] * lv[r >> 2][r & 3];
  }
}

// ---------------- launch ----------------------------------------------------
extern "C" void kernel_launch(void* const* d_in, const int* in_sizes, int n_in,
                              void* d_out, int out_size, void* d_ws, size_t ws_size,
                              hipStream_t stream) {
  const float* x = (const float*)d_in[0];
  const int* mask = (const int*)d_in[1];
  const float* w = (const float*)d_in[2];
  float* outp = (float*)d_out;

  char* ws = (char*)d_ws;
  unsigned short* xb   = (unsigned short*)(ws);                  // 16777216 B
  unsigned short* wT   = (unsigned short*)(ws + 16777216);       //  6291456 B
  unsigned short* Qh   = (unsigned short*)(ws + 23068672);       // 16777216 B
  unsigned short* Kc   = (unsigned short*)(ws + 39845888);       // 16777216 B
  unsigned short* Vtc  = (unsigned short*)(ws + 56623104);       // 16777216 B
  int*            inv  = (int*)(ws + 73400320);                  //    32768 B
  unsigned short* penc = (unsigned short*)(ws + 73433088);       //    16384 B
  int*            nkp  = (int*)(ws + 73449472);                  //       32 B

  build_keep<<<dim3(8), 256, 0, stream>>>(mask, inv, penc, nkp);
  cvt_x<<<dim3(8192), 256, 0, stream>>>(x, xb);
  transpose_w<<<dim3(16, 48), 256, 0, stream>>>(w, wT);
  qkv_gemm<<<dim3(1536), 256, 0, stream>>>(xb, wT, inv, Qh, Kc, Vtc);
  attn_fwd3<<<dim3(1024), 256, 0, stream>>>(Qh, Kc, Vtc, penc, nkp, outp);
}

// Round 6
// 175.282 us; speedup vs baseline: 1.1067x; 1.1067x over previous
//
#include <hip/hip_runtime.h>
#include <hip/hip_bf16.h>
#include <stdint.h>

#define HEADS 16
#define DH    64
#define SEQ   1024
#define DIM   1024

typedef __attribute__((ext_vector_type(8))) short bf16x8;
typedef __attribute__((ext_vector_type(4))) float f32x4;
typedef __attribute__((ext_vector_type(16))) float f32x16;
typedef __attribute__((ext_vector_type(4))) unsigned int u32x4;

// 0.125 * log2(e): folded into Q at GEMM epilogue so softmax uses exp2 directly
#define QSCALE_L2 0.18033688011112042f
// 8 nats in log2 units (defer-max threshold, T13)
#define THR_L2 11.541560327111707f
#define PEN_L2 (-14427.0f)   // -10000 * log2(e)

static __device__ __forceinline__ unsigned short f2bf(float f) {
  unsigned u = __builtin_bit_cast(unsigned, f);
  u += 0x7fff + ((u >> 16) & 1);   // RNE
  return (unsigned short)(u >> 16);
}

static __device__ __forceinline__ float fexp2(float x) {
#if __has_builtin(__builtin_amdgcn_exp2f)
  return __builtin_amdgcn_exp2f(x);
#else
  return exp2f(x);
#endif
}

static __device__ __forceinline__ void gload_lds16(const void* g, void* l) {
  __builtin_amdgcn_global_load_lds(
      (const __attribute__((address_space(1))) unsigned int*)g,
      (__attribute__((address_space(3))) unsigned int*)l,
      16, 0, 0);
}

// ---------------- Kernel B: keep-list scan per batch -------------------------
// inv[b][n] = compact index (or -1 if masked out); penc[b][i] = 0 / -14427 bf16
__global__ __launch_bounds__(256) void build_keep(
    const int* __restrict__ mask, int* __restrict__ inv,
    unsigned short* __restrict__ penc, int* __restrict__ nkeep) {
  const int b = blockIdx.x;
  const int t = threadIdx.x;
  __shared__ int sc[256];
  int kept[4];
  int c = 0;
#pragma unroll
  for (int k = 0; k < 4; ++k) {
    const int j = t * 4 + k;
    const int kp = (j == 0) ? 1 : (mask[b * (SEQ - 1) + j - 1] != 0);
    kept[k] = kp;
    c += kp;
  }
  sc[t] = c;
  __syncthreads();
  for (int off = 1; off < 256; off <<= 1) {
    const int v = (t >= off) ? sc[t - off] : 0;
    __syncthreads();
    sc[t] += v;
    __syncthreads();
  }
  int pos = sc[t] - c;          // exclusive prefix
  const int total = sc[255];
#pragma unroll
  for (int k = 0; k < 4; ++k) {
    const int j = t * 4 + k;
    if (kept[k]) {
      inv[b * SEQ + j] = pos++;
    } else {
      inv[b * SEQ + j] = -1;
    }
  }
#pragma unroll
  for (int k = 0; k < 4; ++k) {
    const int i = t * 4 + k;
    penc[b * SEQ + i] = (i < total) ? (unsigned short)0 : f2bf(PEN_L2);
  }
  if (t == 0) nkeep[b] = total;
}

// ---------------- Kernel A: x f32 -> bf16 -----------------------------------
__global__ __launch_bounds__(256) void cvt_x(
    const float* __restrict__ in, unsigned short* __restrict__ out) {
  const int i = (blockIdx.x * 256 + threadIdx.x) * 4;
  const float4 v = *reinterpret_cast<const float4*>(in + i);
  short4 o;
  o.x = (short)f2bf(v.x);
  o.y = (short)f2bf(v.y);
  o.z = (short)f2bf(v.z);
  o.w = (short)f2bf(v.w);
  *reinterpret_cast<short4*>(out + i) = o;
}

// ---------------- Kernel 0: w f32 [1024][3072] -> wT bf16 [3072][1024] ------
__global__ __launch_bounds__(256) void transpose_w(
    const float* __restrict__ w, unsigned short* __restrict__ wT) {
  __shared__ unsigned short t[64][68];
  const int tid = threadIdx.x;
  const int bk = blockIdx.x;
  const int bn = blockIdx.y;
  const int r = tid >> 4;
  const int c = (tid & 15) * 4;
#pragma unroll
  for (int rr = 0; rr < 64; rr += 16) {
    const float4 v = *reinterpret_cast<const float4*>(
        w + (size_t)(bk * 64 + r + rr) * 3072 + bn * 64 + c);
    t[r + rr][c + 0] = f2bf(v.x);
    t[r + rr][c + 1] = f2bf(v.y);
    t[r + rr][c + 2] = f2bf(v.z);
    t[r + rr][c + 3] = f2bf(v.w);
  }
  __syncthreads();
#pragma unroll
  for (int rr = 0; rr < 64; rr += 16) {
    short4 o;
    o.x = (short)t[c + 0][r + rr];
    o.y = (short)t[c + 1][r + rr];
    o.z = (short)t[c + 2][r + rr];
    o.w = (short)t[c + 3][r + rr];
    *reinterpret_cast<short4*>(
        wT + (size_t)(bn * 64 + r + rr) * 1024 + bk * 64 + c) = o;
  }
}

// ---------------- Kernel 1: qkv = x @ w, scattered to Qh/Kc/Vtc -------------
// Qh: [b,h,n,64] PRE-SCALED by 0.125*log2e ; Kc: [b,h,i,64]; Vtc: [b,h,64,i]
// K/V rows are written at COMPACT position inv[b][n] (skipped if masked out).
// N-tile is 128-wide and 128 | 1024, so each block's columns live in ONE
// section (q/k/v): sec = n0>>10 is block-uniform -> specialized epilogues.
// Grid: dim3(64,24) NATURAL order — measured L2-optimal (round-5 swizzle
// experiment: remap quadrupled FETCH_SIZE; default round-robin keeps each
// XCD's x-slice L2-resident across n-panel passes). Do not swizzle.
__global__ __launch_bounds__(256) void qkv_gemm(
    const unsigned short* __restrict__ x, const unsigned short* __restrict__ wT,
    const int* __restrict__ inv,
    unsigned short* __restrict__ Qh, unsigned short* __restrict__ Kc,
    unsigned short* __restrict__ Vtc) {
  __shared__ unsigned short Al[128 * 32];
  __shared__ unsigned short Bl[128 * 32];
  const int tid = threadIdx.x;
  const int lane = tid & 63;
  const int wave = tid >> 6;
  const int m0 = blockIdx.x * 128;       // 64 M-tiles
  const int n0 = blockIdx.y * 128;       // 24 N-tiles
  const int wm = (wave >> 1) * 64;
  const int wn = (wave & 1) * 64;
  const int l15 = lane & 15;
  const int kb8 = (lane >> 4) * 8;

  f32x4 acc[4][4] = {};

  for (int kt = 0; kt < DIM; kt += 32) {
    __syncthreads();
#pragma unroll
    for (int rnd = 0; rnd < 2; ++rnd) {
      const int off = tid * 16 + rnd * 4096;
      const int row = off >> 6;
      const int kc = (off & 63) >> 1;
      gload_lds16(x + (size_t)(m0 + row) * DIM + kt + kc, (char*)Al + off);
      gload_lds16(wT + (size_t)(n0 + row) * DIM + kt + kc, (char*)Bl + off);
    }
    __syncthreads();
    bf16x8 af[4], bfr[4];
#pragma unroll
    for (int i = 0; i < 4; ++i)
      af[i] = *reinterpret_cast<const bf16x8*>(&Al[(wm + i * 16 + l15) * 32 + kb8]);
#pragma unroll
    for (int j = 0; j < 4; ++j)
      bfr[j] = *reinterpret_cast<const bf16x8*>(&Bl[(wn + j * 16 + l15) * 32 + kb8]);
#pragma unroll
    for (int i = 0; i < 4; ++i)
#pragma unroll
      for (int j = 0; j < 4; ++j)
        acc[i][j] = __builtin_amdgcn_mfma_f32_16x16x32_bf16(af[i], bfr[j], acc[i][j], 0, 0, 0);
  }

  const int sec = n0 >> 10;              // block-uniform: 0=q 1=k 2=v
  if (sec == 0) {
#pragma unroll
    for (int i = 0; i < 4; ++i) {
#pragma unroll
      for (int j = 0; j < 4; ++j) {
        const int col = n0 + wn + j * 16 + l15;
        const int h = (col >> 6) & 15;
        const int dh = col & 63;
#pragma unroll
        for (int r = 0; r < 4; ++r) {
          const int rowg = m0 + wm + i * 16 + (lane >> 4) * 4 + r;
          const int b = rowg >> 10;
          const int n = rowg & 1023;
          Qh[(((size_t)b * HEADS + h) * SEQ + n) * DH + dh] =
              f2bf(acc[i][j][r] * QSCALE_L2);
        }
      }
    }
  } else {
    int ivr[4][4];
#pragma unroll
    for (int i = 0; i < 4; ++i)
#pragma unroll
      for (int r = 0; r < 4; ++r) {
        const int rowg = m0 + wm + i * 16 + (lane >> 4) * 4 + r;
        ivr[i][r] = inv[(rowg >> 10) * SEQ + (rowg & 1023)];
      }
    if (sec == 1) {
#pragma unroll
      for (int i = 0; i < 4; ++i) {
#pragma unroll
        for (int j = 0; j < 4; ++j) {
          const int col = n0 + wn + j * 16 + l15;
          const int h = (col >> 6) & 15;
          const int dh = col & 63;
#pragma unroll
          for (int r = 0; r < 4; ++r) {
            const int rowg = m0 + wm + i * 16 + (lane >> 4) * 4 + r;
            const int b = rowg >> 10;
            const int iv = ivr[i][r];
            if (iv >= 0)
              Kc[(((size_t)b * HEADS + h) * SEQ + iv) * DH + dh] =
                  f2bf(acc[i][j][r]);
          }
        }
      }
    } else {
#pragma unroll
      for (int i = 0; i < 4; ++i) {
#pragma unroll
        for (int j = 0; j < 4; ++j) {
          const int col = n0 + wn + j * 16 + l15;
          const int h = (col >> 6) & 15;
          const int dh = col & 63;
#pragma unroll
          for (int r = 0; r < 4; ++r) {
            const int rowg = m0 + wm + i * 16 + (lane >> 4) * 4 + r;
            const int b = rowg >> 10;
            const int iv = ivr[i][r];
            if (iv >= 0)
              Vtc[(((size_t)b * HEADS + h) * DH + dh) * SEQ + iv] =
                  f2bf(acc[i][j][r]);
          }
        }
      }
    }
  }
}

// ---------------- Kernel 2: flash attention over compacted KV ---------------
// block = 4 waves x 32 q-rows of one (b,h); 32x32x16 MFMA; K-frag double buffer.
__global__ __launch_bounds__(256) void attn_fwd3(
    const unsigned short* __restrict__ Qh, const unsigned short* __restrict__ Kc,
    const unsigned short* __restrict__ Vtc, const unsigned short* __restrict__ penc,
    const int* __restrict__ nkeep, float* __restrict__ out) {
  __shared__ unsigned short penb[SEQ];
  __shared__ float corrw[4][32];
  const int tid = threadIdx.x;
  const int lane = tid & 63;
  const int wave = tid >> 6;
  const int l31 = lane & 31;
  const int h8 = (lane >> 5) * 8;
  const bool islo = lane < 32;

  // XCD swizzle: 128 consecutive logical blocks (16 heads) per XCD
  const int bid = ((blockIdx.x & 7) << 7) | (blockIdx.x >> 3);
  const int b = bid >> 7;
  const int hh = (bid >> 3) & 15;
  const int qc = bid & 7;
  const size_t bh = (size_t)b * HEADS + hh;
  const int q0 = qc * 128 + wave * 32;

  const int nk = nkeep[b];
  const int nt64 = (nk + 63) & ~63;

  for (int j = tid; j < SEQ; j += 256) penb[j] = penc[b * SEQ + j];
  __syncthreads();

  const unsigned short* Q = Qh + bh * SEQ * DH;
  const unsigned short* K = Kc + bh * SEQ * DH;
  const unsigned short* V = Vtc + bh * DH * SEQ;   // [64][1024] compacted cols

  bf16x8 qf[4];
#pragma unroll
  for (int ds = 0; ds < 4; ++ds)
    qf[ds] = *reinterpret_cast<const bf16x8*>(
        Q + (size_t)(q0 + l31) * DH + ds * 16 + h8);

  u32x4 onesu = {0u, 0u, 0u, 0u};
  onesu.x = islo ? 0x3F80u : 0u;     // bf16 1.0 at k==0 of lane-half 0
  const bf16x8 onesf = __builtin_bit_cast(bf16x8, onesu);

  f32x16 Od0 = (f32x16)0.f, Od1 = (f32x16)0.f;
  float m_ = 0.f, l_ = 0.f;

  bf16x8 kfA[8], kfB[8];
  auto loadK = [&](bf16x8* dst, int ktt) {
#pragma unroll
    for (int ds = 0; ds < 4; ++ds) {
      dst[ds]     = *reinterpret_cast<const bf16x8*>(
          K + (size_t)(ktt + l31) * DH + ds * 16 + h8);
      dst[ds + 4] = *reinterpret_cast<const bf16x8*>(
          K + (size_t)(ktt + 32 + l31) * DH + ds * 16 + h8);
    }
  };
  loadK(kfA, 0);

  auto step = [&](const bf16x8* kc, bf16x8* kn, int kt) {
    // V frags issued first: latency hides under QK^T + softmax
    bf16x8 vf[8];
#pragma unroll
    for (int dt = 0; dt < 2; ++dt)
#pragma unroll
      for (int kvs = 0; kvs < 4; ++kvs)
        vf[dt * 4 + kvs] = *reinterpret_cast<const bf16x8*>(
            V + (size_t)(dt * 32 + l31) * SEQ + kt + kvs * 16 + h8);
    // S^T = K·Q^T (log2 units)
    f32x16 st0 = (f32x16)0.f, st1 = (f32x16)0.f;
    __builtin_amdgcn_s_setprio(1);
#pragma unroll
    for (int ds = 0; ds < 4; ++ds) {
      st0 = __builtin_amdgcn_mfma_f32_32x32x16_bf16(kc[ds], qf[ds], st0, 0, 0, 0);
      st1 = __builtin_amdgcn_mfma_f32_32x32x16_bf16(kc[ds + 4], qf[ds], st1, 0, 0, 0);
    }
    __builtin_amdgcn_s_setprio(0);
    // prefetch next K tile (clamped; hides under softmax+pack+PV)
    const int ktn = (kt + 64 < nt64) ? kt + 64 : 0;
    loadK(kn, ktn);
    // tail mask via rank-1 MFMA: st[kv][q] += penb[kv]
    {
      const unsigned short pu0 = penb[kt + l31];
      const unsigned short pu1 = penb[kt + 32 + l31];
      u32x4 p0 = {0u, 0u, 0u, 0u}, p1 = {0u, 0u, 0u, 0u};
      p0.x = islo ? (unsigned)pu0 : 0u;
      p1.x = islo ? (unsigned)pu1 : 0u;
      st0 = __builtin_amdgcn_mfma_f32_32x32x16_bf16(
          __builtin_bit_cast(bf16x8, p0), onesf, st0, 0, 0, 0);
      st1 = __builtin_amdgcn_mfma_f32_32x32x16_bf16(
          __builtin_bit_cast(bf16x8, p1), onesf, st1, 0, 0, 0);
    }
    // row max
    float a[8];
#pragma unroll
    for (int i = 0; i < 8; ++i)
      a[i] = fmaxf(fmaxf(st0[i], st0[i + 8]), fmaxf(st1[i], st1[i + 8]));
#pragma unroll
    for (int k = 4; k >= 1; k >>= 1)
#pragma unroll
      for (int i = 0; i < k; ++i) a[i] = fmaxf(a[i], a[i + k]);
    const float mx = fmaxf(a[0], __shfl_xor(a[0], 32));
    // deferred rescale (rare)
    if (!__all(mx <= m_ + THR_L2)) {
      const float mn = fmaxf(m_, mx);
      const float corr = fexp2(m_ - mn);
      m_ = mn;
      l_ *= corr;
      if (islo) corrw[wave][l31] = corr;
      f32x4 cv[4];
#pragma unroll
      for (int j = 0; j < 4; ++j)
        cv[j] = *reinterpret_cast<const f32x4*>(&corrw[wave][j * 8 + (h8 >> 1)]);
#pragma unroll
      for (int r = 0; r < 16; ++r) {
        Od0[r] *= cv[r >> 2][r & 3];
        Od1[r] *= cv[r >> 2][r & 3];
      }
    }
    // P = exp2(st - m)
#pragma unroll
    for (int i = 0; i < 16; ++i) {
      st0[i] = fexp2(st0[i] - m_);
      st1[i] = fexp2(st1[i] - m_);
    }
    // row sum
    float s8[8];
#pragma unroll
    for (int i = 0; i < 8; ++i)
      s8[i] = (st0[i] + st0[i + 8]) + (st1[i] + st1[i + 8]);
#pragma unroll
    for (int k = 4; k >= 1; k >>= 1)
#pragma unroll
      for (int i = 0; i < k; ++i) s8[i] += s8[i + k];
    l_ += s8[0] + __shfl_xor(s8[0], 32);
    // pack P -> A-frags (cvt_pk + permlane32_swap)
    bf16x8 pf[4];
#pragma unroll
    for (int t = 0; t < 2; ++t) {
#pragma unroll
      for (int bq = 0; bq < 2; ++bq) {
        const int o = 8 * bq;
        float e0 = t ? st1[o + 0] : st0[o + 0], e1 = t ? st1[o + 1] : st0[o + 1];
        float e2 = t ? st1[o + 2] : st0[o + 2], e3 = t ? st1[o + 3] : st0[o + 3];
        float e4 = t ? st1[o + 4] : st0[o + 4], e5 = t ? st1[o + 5] : st0[o + 5];
        float e6 = t ? st1[o + 6] : st0[o + 6], e7 = t ? st1[o + 7] : st0[o + 7];
        unsigned A0, A1, B0, B1;
        asm("v_cvt_pk_bf16_f32 %0, %1, %2" : "=v"(A0) : "v"(e0), "v"(e1));
        asm("v_cvt_pk_bf16_f32 %0, %1, %2" : "=v"(A1) : "v"(e2), "v"(e3));
        asm("v_cvt_pk_bf16_f32 %0, %1, %2" : "=v"(B0) : "v"(e4), "v"(e5));
        asm("v_cvt_pk_bf16_f32 %0, %1, %2" : "=v"(B1) : "v"(e6), "v"(e7));
        asm("v_permlane32_swap_b32 %0, %1\n\ts_nop 1" : "+v"(A0), "+v"(B0));
        asm("v_permlane32_swap_b32 %0, %1\n\ts_nop 1" : "+v"(A1), "+v"(B1));
        u32x4 pk4;
        pk4.x = A0; pk4.y = A1; pk4.z = B0; pk4.w = B1;
        pf[t * 2 + bq] = __builtin_bit_cast(bf16x8, pk4);
      }
    }
    // PV
    __builtin_amdgcn_s_setprio(1);
#pragma unroll
    for (int kvs = 0; kvs < 4; ++kvs) {
      Od0 = __builtin_amdgcn_mfma_f32_32x32x16_bf16(pf[kvs], vf[kvs], Od0, 0, 0, 0);
      Od1 = __builtin_amdgcn_mfma_f32_32x32x16_bf16(pf[kvs], vf[4 + kvs], Od1, 0, 0, 0);
    }
    __builtin_amdgcn_s_setprio(0);
  };

  for (int kt = 0; kt < nt64; kt += 128) {
    step(kfA, kfB, kt);
    if (kt + 64 < nt64) step(kfB, kfA, kt + 64);
  }

  // epilogue: O / l
  if (islo) corrw[wave][l31] = 1.0f / l_;
  f32x4 lv[4];
#pragma unroll
  for (int j = 0; j < 4; ++j)
    lv[j] = *reinterpret_cast<const f32x4*>(&corrw[wave][j * 8 + (h8 >> 1)]);
#pragma unroll
  for (int r = 0; r < 16; ++r) {
    const int q = q0 + (r & 3) + 8 * (r >> 2) + ((lane >> 5) << 2);
    out[((size_t)b * SEQ + q) * (HEADS * DH) + hh * DH + 0 * 32 + l31] =
        Od0[r] * lv[r >> 2][r & 3];
    out[((size_t)b * SEQ + q) * (HEADS * DH) + hh * DH + 1 * 32 + l31] =
        Od1[r] * lv[r >> 2][r & 3];
  }
}

// ---------------- launch ----------------------------------------------------
extern "C" void kernel_launch(void* const* d_in, const int* in_sizes, int n_in,
                              void* d_out, int out_size, void* d_ws, size_t ws_size,
                              hipStream_t stream) {
  const float* x = (const float*)d_in[0];
  const int* mask = (const int*)d_in[1];
  const float* w = (const float*)d_in[2];
  float* outp = (float*)d_out;

  char* ws = (char*)d_ws;
  unsigned short* xb   = (unsigned short*)(ws);                  // 16777216 B
  unsigned short* wT   = (unsigned short*)(ws + 16777216);       //  6291456 B
  unsigned short* Qh   = (unsigned short*)(ws + 23068672);       // 16777216 B
  unsigned short* Kc   = (unsigned short*)(ws + 39845888);       // 16777216 B
  unsigned short* Vtc  = (unsigned short*)(ws + 56623104);       // 16777216 B
  int*            inv  = (int*)(ws + 73400320);                  //    32768 B
  unsigned short* penc = (unsigned short*)(ws + 73433088);       //    16384 B
  int*            nkp  = (int*)(ws + 73449472);                  //       32 B

  build_keep<<<dim3(8), 256, 0, stream>>>(mask, inv, penc, nkp);
  cvt_x<<<dim3(8192), 256, 0, stream>>>(x, xb);
  transpose_w<<<dim3(16, 48), 256, 0, stream>>>(w, wT);
  qkv_gemm<<<dim3(64, 24), 256, 0, stream>>>(xb, wT, inv, Qh, Kc, Vtc);
  attn_fwd3<<<dim3(1024), 256, 0, stream>>>(Qh, Kc, Vtc, penc, nkp, outp);
}

// Round 7
// 140.672 us; speedup vs baseline: 1.3790x; 1.2460x over previous
//
#include <hip/hip_runtime.h>
#include <hip/hip_bf16.h>
#include <stdint.h>

#define HEADS 16
#define DH    64
#define SEQ   1024
#define DIM   1024

typedef __attribute__((ext_vector_type(8))) short bf16x8;
typedef __attribute__((ext_vector_type(4))) float f32x4;
typedef __attribute__((ext_vector_type(16))) float f32x16;
typedef __attribute__((ext_vector_type(4))) unsigned int u32x4;

// 0.125 * log2(e): folded into Q at GEMM epilogue so softmax uses exp2 directly
#define QSCALE_L2 0.18033688011112042f
// 8 nats in log2 units (defer-max threshold, T13)
#define THR_L2 11.541560327111707f
#define PEN_L2 (-14427.0f)   // -10000 * log2(e)

static __device__ __forceinline__ unsigned short f2bf(float f) {
  unsigned u = __builtin_bit_cast(unsigned, f);
  u += 0x7fff + ((u >> 16) & 1);   // RNE
  return (unsigned short)(u >> 16);
}

static __device__ __forceinline__ float fexp2(float x) {
#if __has_builtin(__builtin_amdgcn_exp2f)
  return __builtin_amdgcn_exp2f(x);
#else
  return exp2f(x);
#endif
}

static __device__ __forceinline__ void gload_lds16(const void* g, void* l) {
  __builtin_amdgcn_global_load_lds(
      (const __attribute__((address_space(1))) unsigned int*)g,
      (__attribute__((address_space(3))) unsigned int*)l,
      16, 0, 0);
}

// ---------------- Kernel B: keep-list scan per batch -------------------------
// inv[b][n] = compact index (or -1 if masked out); penc[b][i] = 0 / -14427 bf16
__global__ __launch_bounds__(256) void build_keep(
    const int* __restrict__ mask, int* __restrict__ inv,
    unsigned short* __restrict__ penc, int* __restrict__ nkeep) {
  const int b = blockIdx.x;
  const int t = threadIdx.x;
  __shared__ int sc[256];
  int kept[4];
  int c = 0;
#pragma unroll
  for (int k = 0; k < 4; ++k) {
    const int j = t * 4 + k;
    const int kp = (j == 0) ? 1 : (mask[b * (SEQ - 1) + j - 1] != 0);
    kept[k] = kp;
    c += kp;
  }
  sc[t] = c;
  __syncthreads();
  for (int off = 1; off < 256; off <<= 1) {
    const int v = (t >= off) ? sc[t - off] : 0;
    __syncthreads();
    sc[t] += v;
    __syncthreads();
  }
  int pos = sc[t] - c;          // exclusive prefix
  const int total = sc[255];
#pragma unroll
  for (int k = 0; k < 4; ++k) {
    const int j = t * 4 + k;
    if (kept[k]) {
      inv[b * SEQ + j] = pos++;
    } else {
      inv[b * SEQ + j] = -1;
    }
  }
#pragma unroll
  for (int k = 0; k < 4; ++k) {
    const int i = t * 4 + k;
    penc[b * SEQ + i] = (i < total) ? (unsigned short)0 : f2bf(PEN_L2);
  }
  if (t == 0) nkeep[b] = total;
}

// ---------------- Kernel A: x f32 -> bf16 -----------------------------------
__global__ __launch_bounds__(256) void cvt_x(
    const float* __restrict__ in, unsigned short* __restrict__ out) {
  const int i = (blockIdx.x * 256 + threadIdx.x) * 4;
  const float4 v = *reinterpret_cast<const float4*>(in + i);
  short4 o;
  o.x = (short)f2bf(v.x);
  o.y = (short)f2bf(v.y);
  o.z = (short)f2bf(v.z);
  o.w = (short)f2bf(v.w);
  *reinterpret_cast<short4*>(out + i) = o;
}

// ---------------- Kernel 0: w f32 [1024][3072] -> wT bf16 [3072][1024] ------
__global__ __launch_bounds__(256) void transpose_w(
    const float* __restrict__ w, unsigned short* __restrict__ wT) {
  __shared__ unsigned short t[64][68];
  const int tid = threadIdx.x;
  const int bk = blockIdx.x;
  const int bn = blockIdx.y;
  const int r = tid >> 4;
  const int c = (tid & 15) * 4;
#pragma unroll
  for (int rr = 0; rr < 64; rr += 16) {
    const float4 v = *reinterpret_cast<const float4*>(
        w + (size_t)(bk * 64 + r + rr) * 3072 + bn * 64 + c);
    t[r + rr][c + 0] = f2bf(v.x);
    t[r + rr][c + 1] = f2bf(v.y);
    t[r + rr][c + 2] = f2bf(v.z);
    t[r + rr][c + 3] = f2bf(v.w);
  }
  __syncthreads();
#pragma unroll
  for (int rr = 0; rr < 64; rr += 16) {
    short4 o;
    o.x = (short)t[c + 0][r + rr];
    o.y = (short)t[c + 1][r + rr];
    o.z = (short)t[c + 2][r + rr];
    o.w = (short)t[c + 3][r + rr];
    *reinterpret_cast<short4*>(
        wT + (size_t)(bn * 64 + r + rr) * 1024 + bk * 64 + c) = o;
  }
}

// ---------------- Kernel 1: qkv = x @ w, scattered to Qh/Kc/Vtc -------------
// Qh: [b,h,n,64] PRE-SCALED by 0.125*log2e ; Kc: [b,h,i,64]; Vtc: [b,h,64,i]
// K/V rows are written at COMPACT position inv[b][n] (skipped if masked out).
// Grid: dim3(64,24) NATURAL order — measured L2-optimal (round-5 swizzle
// experiment: remap quadrupled FETCH_SIZE). Do not swizzle.
__global__ __launch_bounds__(256) void qkv_gemm(
    const unsigned short* __restrict__ x, const unsigned short* __restrict__ wT,
    const int* __restrict__ inv,
    unsigned short* __restrict__ Qh, unsigned short* __restrict__ Kc,
    unsigned short* __restrict__ Vtc) {
  __shared__ unsigned short Al[128 * 32];
  __shared__ unsigned short Bl[128 * 32];
  const int tid = threadIdx.x;
  const int lane = tid & 63;
  const int wave = tid >> 6;
  const int m0 = blockIdx.x * 128;       // 64 M-tiles
  const int n0 = blockIdx.y * 128;       // 24 N-tiles
  const int wm = (wave >> 1) * 64;
  const int wn = (wave & 1) * 64;
  const int l15 = lane & 15;
  const int kb8 = (lane >> 4) * 8;

  f32x4 acc[4][4] = {};

  for (int kt = 0; kt < DIM; kt += 32) {
    __syncthreads();
#pragma unroll
    for (int rnd = 0; rnd < 2; ++rnd) {
      const int off = tid * 16 + rnd * 4096;
      const int row = off >> 6;
      const int kc = (off & 63) >> 1;
      gload_lds16(x + (size_t)(m0 + row) * DIM + kt + kc, (char*)Al + off);
      gload_lds16(wT + (size_t)(n0 + row) * DIM + kt + kc, (char*)Bl + off);
    }
    __syncthreads();
    bf16x8 af[4], bfr[4];
#pragma unroll
    for (int i = 0; i < 4; ++i)
      af[i] = *reinterpret_cast<const bf16x8*>(&Al[(wm + i * 16 + l15) * 32 + kb8]);
#pragma unroll
    for (int j = 0; j < 4; ++j)
      bfr[j] = *reinterpret_cast<const bf16x8*>(&Bl[(wn + j * 16 + l15) * 32 + kb8]);
#pragma unroll
    for (int i = 0; i < 4; ++i)
#pragma unroll
      for (int j = 0; j < 4; ++j)
        acc[i][j] = __builtin_amdgcn_mfma_f32_16x16x32_bf16(af[i], bfr[j], acc[i][j], 0, 0, 0);
  }

  const int sec = n0 >> 10;              // block-uniform: 0=q 1=k 2=v
  if (sec == 0) {
#pragma unroll
    for (int i = 0; i < 4; ++i) {
#pragma unroll
      for (int j = 0; j < 4; ++j) {
        const int col = n0 + wn + j * 16 + l15;
        const int h = (col >> 6) & 15;
        const int dh = col & 63;
#pragma unroll
        for (int r = 0; r < 4; ++r) {
          const int rowg = m0 + wm + i * 16 + (lane >> 4) * 4 + r;
          const int b = rowg >> 10;
          const int n = rowg & 1023;
          Qh[(((size_t)b * HEADS + h) * SEQ + n) * DH + dh] =
              f2bf(acc[i][j][r] * QSCALE_L2);
        }
      }
    }
  } else {
    int ivr[4][4];
#pragma unroll
    for (int i = 0; i < 4; ++i)
#pragma unroll
      for (int r = 0; r < 4; ++r) {
        const int rowg = m0 + wm + i * 16 + (lane >> 4) * 4 + r;
        ivr[i][r] = inv[(rowg >> 10) * SEQ + (rowg & 1023)];
      }
    if (sec == 1) {
#pragma unroll
      for (int i = 0; i < 4; ++i) {
#pragma unroll
        for (int j = 0; j < 4; ++j) {
          const int col = n0 + wn + j * 16 + l15;
          const int h = (col >> 6) & 15;
          const int dh = col & 63;
#pragma unroll
          for (int r = 0; r < 4; ++r) {
            const int rowg = m0 + wm + i * 16 + (lane >> 4) * 4 + r;
            const int b = rowg >> 10;
            const int iv = ivr[i][r];
            if (iv >= 0)
              Kc[(((size_t)b * HEADS + h) * SEQ + iv) * DH + dh] =
                  f2bf(acc[i][j][r]);
          }
        }
      }
    } else {
#pragma unroll
      for (int i = 0; i < 4; ++i) {
#pragma unroll
        for (int j = 0; j < 4; ++j) {
          const int col = n0 + wn + j * 16 + l15;
          const int h = (col >> 6) & 15;
          const int dh = col & 63;
#pragma unroll
          for (int r = 0; r < 4; ++r) {
            const int rowg = m0 + wm + i * 16 + (lane >> 4) * 4 + r;
            const int b = rowg >> 10;
            const int iv = ivr[i][r];
            if (iv >= 0)
              Vtc[(((size_t)b * HEADS + h) * DH + dh) * SEQ + iv] =
                  f2bf(acc[i][j][r]);
          }
        }
      }
    }
  }
}

// ---------------- Kernel 2: flash attention over compacted KV ---------------
// block = 4 waves x 32 q-rows of one (b,h); 32x32x16 MFMA.
// K and V tiles staged cooperatively in double-buffered LDS via
// global_load_lds (ONE copy per block instead of one per wave).
// LDS tiles are [64 rows][128 B]; XOR chunk-swizzle (chunk ^= row&7) applied
// on the GLOBAL source address (gload_lds dest must stay linear) and again
// on the ds_read address — breaks the 32-way bank conflict down to ~4-way.
__global__ __launch_bounds__(256) void attn_fwd4(
    const unsigned short* __restrict__ Qh, const unsigned short* __restrict__ Kc,
    const unsigned short* __restrict__ Vtc, const unsigned short* __restrict__ penc,
    const int* __restrict__ nkeep, float* __restrict__ out) {
  __shared__ alignas(16) unsigned char Kl[2][8192];
  __shared__ alignas(16) unsigned char Vl[2][8192];
  __shared__ unsigned short penb[SEQ];
  __shared__ float corrw[4][32];
  const int tid = threadIdx.x;
  const int lane = tid & 63;
  const int wave = tid >> 6;
  const int l31 = lane & 31;
  const int hi = lane >> 5;          // lane-half
  const int h8 = hi * 8;             // k-offset of this lane-half in A/B frags
  const bool islo = lane < 32;

  // XCD swizzle: 128 consecutive logical blocks (16 heads) per XCD
  const int bid = ((blockIdx.x & 7) << 7) | (blockIdx.x >> 3);
  const int b = bid >> 7;
  const int hh = (bid >> 3) & 15;
  const int qc = bid & 7;
  const size_t bh = (size_t)b * HEADS + hh;
  const int q0 = qc * 128 + wave * 32;

  const int nk = nkeep[b];
  const int ntile = (nk + 63) >> 6;

  const unsigned short* Q = Qh + bh * SEQ * DH;
  const unsigned short* K = Kc + bh * SEQ * DH;
  const unsigned short* V = Vtc + bh * DH * SEQ;   // [64][1024] compacted cols

  // cooperative stage of one 64-kv tile of K and V into LDS buffer `buf`
  auto STAGE = [&](int buf, int kt) {
#pragma unroll
    for (int p = 0; p < 2; ++p) {
      const int off = p * 4096 + tid * 16;      // byte offset in 8KB tile
      const int row = off >> 7;                 // 0..63
      const int chunk = (off >> 4) & 7;
      const int sch = chunk ^ (row & 7);        // source-side swizzle
      gload_lds16(K + (size_t)(kt + row) * DH + sch * 8, &Kl[buf][off]);
      gload_lds16(V + (size_t)row * SEQ + kt + sch * 8, &Vl[buf][off]);
    }
  };

  STAGE(0, 0);
  for (int j = tid; j < SEQ; j += 256) penb[j] = penc[b * SEQ + j];

  bf16x8 qf[4];
#pragma unroll
  for (int ds = 0; ds < 4; ++ds)
    qf[ds] = *reinterpret_cast<const bf16x8*>(
        Q + (size_t)(q0 + l31) * DH + ds * 16 + h8);

  u32x4 onesu = {0u, 0u, 0u, 0u};
  onesu.x = islo ? 0x3F80u : 0u;     // bf16 1.0 at k==0 of lane-half 0
  const bf16x8 onesf = __builtin_bit_cast(bf16x8, onesu);

  f32x16 Od0 = (f32x16)0.f, Od1 = (f32x16)0.f;
  float m_ = 0.f, l_ = 0.f;

  __syncthreads();   // drains prologue STAGE (vmcnt0) + penb

  int cur = 0;
  for (int ti = 0; ti < ntile; ++ti) {
    const int kt = ti * 64;
    if (ti + 1 < ntile) STAGE(cur ^ 1, kt + 64);

    // ---- S^T = K·Q^T from LDS (swizzled ds_read_b128) ----
    f32x16 st0 = (f32x16)0.f, st1 = (f32x16)0.f;
    __builtin_amdgcn_s_setprio(1);
#pragma unroll
    for (int ds = 0; ds < 4; ++ds) {
      const int c0 = (ds * 2 + hi) ^ (l31 & 7);       // rows 0..31 (row&7 == l31&7)
      const bf16x8 kf0 = *reinterpret_cast<const bf16x8*>(
          &Kl[cur][l31 * 128 + c0 * 16]);
      st0 = __builtin_amdgcn_mfma_f32_32x32x16_bf16(kf0, qf[ds], st0, 0, 0, 0);
      const bf16x8 kf1 = *reinterpret_cast<const bf16x8*>(
          &Kl[cur][(32 + l31) * 128 + c0 * 16]);
      st1 = __builtin_amdgcn_mfma_f32_32x32x16_bf16(kf1, qf[ds], st1, 0, 0, 0);
    }
    __builtin_amdgcn_s_setprio(0);

    // tail mask via rank-1 MFMA: st[kv][q] += penb[kv]
    {
      const unsigned short pu0 = penb[kt + l31];
      const unsigned short pu1 = penb[kt + 32 + l31];
      u32x4 p0 = {0u, 0u, 0u, 0u}, p1 = {0u, 0u, 0u, 0u};
      p0.x = islo ? (unsigned)pu0 : 0u;
      p1.x = islo ? (unsigned)pu1 : 0u;
      st0 = __builtin_amdgcn_mfma_f32_32x32x16_bf16(
          __builtin_bit_cast(bf16x8, p0), onesf, st0, 0, 0, 0);
      st1 = __builtin_amdgcn_mfma_f32_32x32x16_bf16(
          __builtin_bit_cast(bf16x8, p1), onesf, st1, 0, 0, 0);
    }
    // row max
    float a[8];
#pragma unroll
    for (int i = 0; i < 8; ++i)
      a[i] = fmaxf(fmaxf(st0[i], st0[i + 8]), fmaxf(st1[i], st1[i + 8]));
#pragma unroll
    for (int k = 4; k >= 1; k >>= 1)
#pragma unroll
      for (int i = 0; i < k; ++i) a[i] = fmaxf(a[i], a[i + k]);
    const float mx = fmaxf(a[0], __shfl_xor(a[0], 32));
    // deferred rescale (rare)
    if (!__all(mx <= m_ + THR_L2)) {
      const float mn = fmaxf(m_, mx);
      const float corr = fexp2(m_ - mn);
      m_ = mn;
      l_ *= corr;
      if (islo) corrw[wave][l31] = corr;
      f32x4 cv[4];
#pragma unroll
      for (int j = 0; j < 4; ++j)
        cv[j] = *reinterpret_cast<const f32x4*>(&corrw[wave][j * 8 + (h8 >> 1)]);
#pragma unroll
      for (int r = 0; r < 16; ++r) {
        Od0[r] *= cv[r >> 2][r & 3];
        Od1[r] *= cv[r >> 2][r & 3];
      }
    }
    // P = exp2(st - m)
#pragma unroll
    for (int i = 0; i < 16; ++i) {
      st0[i] = fexp2(st0[i] - m_);
      st1[i] = fexp2(st1[i] - m_);
    }
    // row sum
    float s8[8];
#pragma unroll
    for (int i = 0; i < 8; ++i)
      s8[i] = (st0[i] + st0[i + 8]) + (st1[i] + st1[i + 8]);
#pragma unroll
    for (int k = 4; k >= 1; k >>= 1)
#pragma unroll
      for (int i = 0; i < k; ++i) s8[i] += s8[i + k];
    l_ += s8[0] + __shfl_xor(s8[0], 32);
    // pack P -> A-frags (cvt_pk + permlane32_swap)
    bf16x8 pf[4];
#pragma unroll
    for (int t = 0; t < 2; ++t) {
#pragma unroll
      for (int bq = 0; bq < 2; ++bq) {
        const int o = 8 * bq;
        float e0 = t ? st1[o + 0] : st0[o + 0], e1 = t ? st1[o + 1] : st0[o + 1];
        float e2 = t ? st1[o + 2] : st0[o + 2], e3 = t ? st1[o + 3] : st0[o + 3];
        float e4 = t ? st1[o + 4] : st0[o + 4], e5 = t ? st1[o + 5] : st0[o + 5];
        float e6 = t ? st1[o + 6] : st0[o + 6], e7 = t ? st1[o + 7] : st0[o + 7];
        unsigned A0, A1, B0, B1;
        asm("v_cvt_pk_bf16_f32 %0, %1, %2" : "=v"(A0) : "v"(e0), "v"(e1));
        asm("v_cvt_pk_bf16_f32 %0, %1, %2" : "=v"(A1) : "v"(e2), "v"(e3));
        asm("v_cvt_pk_bf16_f32 %0, %1, %2" : "=v"(B0) : "v"(e4), "v"(e5));
        asm("v_cvt_pk_bf16_f32 %0, %1, %2" : "=v"(B1) : "v"(e6), "v"(e7));
        asm("v_permlane32_swap_b32 %0, %1\n\ts_nop 1" : "+v"(A0), "+v"(B0));
        asm("v_permlane32_swap_b32 %0, %1\n\ts_nop 1" : "+v"(A1), "+v"(B1));
        u32x4 pk4;
        pk4.x = A0; pk4.y = A1; pk4.z = B0; pk4.w = B1;
        pf[t * 2 + bq] = __builtin_bit_cast(bf16x8, pk4);
      }
    }
    // ---- PV from LDS V tile (swizzled ds_read_b128) ----
    __builtin_amdgcn_s_setprio(1);
#pragma unroll
    for (int kvs = 0; kvs < 4; ++kvs) {
      const int c0 = (kvs * 2 + hi) ^ (l31 & 7);
      const bf16x8 v0 = *reinterpret_cast<const bf16x8*>(
          &Vl[cur][l31 * 128 + c0 * 16]);
      Od0 = __builtin_amdgcn_mfma_f32_32x32x16_bf16(pf[kvs], v0, Od0, 0, 0, 0);
      const bf16x8 v1 = *reinterpret_cast<const bf16x8*>(
          &Vl[cur][(32 + l31) * 128 + c0 * 16]);
      Od1 = __builtin_amdgcn_mfma_f32_32x32x16_bf16(pf[kvs], v1, Od1, 0, 0, 0);
    }
    __builtin_amdgcn_s_setprio(0);

    __syncthreads();   // drains STAGE(cur^1) + all waves done reading cur
    cur ^= 1;
  }

  // epilogue: O / l
  if (islo) corrw[wave][l31] = 1.0f / l_;
  f32x4 lv[4];
#pragma unroll
  for (int j = 0; j < 4; ++j)
    lv[j] = *reinterpret_cast<const f32x4*>(&corrw[wave][j * 8 + (h8 >> 1)]);
#pragma unroll
  for (int r = 0; r < 16; ++r) {
    const int q = q0 + (r & 3) + 8 * (r >> 2) + (hi << 2);
    out[((size_t)b * SEQ + q) * (HEADS * DH) + hh * DH + 0 * 32 + l31] =
        Od0[r] * lv[r >> 2][r & 3];
    out[((size_t)b * SEQ + q) * (HEADS * DH) + hh * DH + 1 * 32 + l31] =
        Od1[r] * lv[r >> 2][r & 3];
  }
}

// ---------------- launch ----------------------------------------------------
extern "C" void kernel_launch(void* const* d_in, const int* in_sizes, int n_in,
                              void* d_out, int out_size, void* d_ws, size_t ws_size,
                              hipStream_t stream) {
  const float* x = (const float*)d_in[0];
  const int* mask = (const int*)d_in[1];
  const float* w = (const float*)d_in[2];
  float* outp = (float*)d_out;

  char* ws = (char*)d_ws;
  unsigned short* xb   = (unsigned short*)(ws);                  // 16777216 B
  unsigned short* wT   = (unsigned short*)(ws + 16777216);       //  6291456 B
  unsigned short* Qh   = (unsigned short*)(ws + 23068672);       // 16777216 B
  unsigned short* Kc   = (unsigned short*)(ws + 39845888);       // 16777216 B
  unsigned short* Vtc  = (unsigned short*)(ws + 56623104);       // 16777216 B
  int*            inv  = (int*)(ws + 73400320);                  //    32768 B
  unsigned short* penc = (unsigned short*)(ws + 73433088);       //    16384 B
  int*            nkp  = (int*)(ws + 73449472);                  //       32 B

  build_keep<<<dim3(8), 256, 0, stream>>>(mask, inv, penc, nkp);
  cvt_x<<<dim3(8192), 256, 0, stream>>>(x, xb);
  transpose_w<<<dim3(16, 48), 256, 0, stream>>>(w, wT);
  qkv_gemm<<<dim3(64, 24), 256, 0, stream>>>(xb, wT, inv, Qh, Kc, Vtc);
  attn_fwd4<<<dim3(1024), 256, 0, stream>>>(Qh, Kc, Vtc, penc, nkp, outp);
}

// Round 8
// 131.707 us; speedup vs baseline: 1.4729x; 1.0681x over previous
//
#include <hip/hip_runtime.h>
#include <hip/hip_bf16.h>
#include <stdint.h>

#define HEADS 16
#define DH    64
#define SEQ   1024
#define DIM   1024

typedef __attribute__((ext_vector_type(8))) short bf16x8;
typedef __attribute__((ext_vector_type(4))) float f32x4;
typedef __attribute__((ext_vector_type(16))) float f32x16;
typedef __attribute__((ext_vector_type(4))) unsigned int u32x4;

// 0.125 * log2(e): folded into Q at GEMM epilogue so softmax uses exp2 directly
#define QSCALE_L2 0.18033688011112042f
// 8 nats in log2 units (defer-max threshold, T13)
#define THR_L2 11.541560327111707f
#define PEN_L2 (-14427.0f)   // -10000 * log2(e)

static __device__ __forceinline__ unsigned short f2bf(float f) {
  unsigned u = __builtin_bit_cast(unsigned, f);
  u += 0x7fff + ((u >> 16) & 1);   // RNE
  return (unsigned short)(u >> 16);
}

static __device__ __forceinline__ float fexp2(float x) {
#if __has_builtin(__builtin_amdgcn_exp2f)
  return __builtin_amdgcn_exp2f(x);
#else
  return exp2f(x);
#endif
}

static __device__ __forceinline__ void gload_lds16(const void* g, void* l) {
  __builtin_amdgcn_global_load_lds(
      (const __attribute__((address_space(1))) unsigned int*)g,
      (__attribute__((address_space(3))) unsigned int*)l,
      16, 0, 0);
}

// ---------------- Kernel B: keep-list scan per batch -------------------------
// inv[b][n] = compact index (or -1 if masked out)
__global__ __launch_bounds__(256) void build_keep(
    const int* __restrict__ mask, int* __restrict__ inv, int* __restrict__ nkeep) {
  const int b = blockIdx.x;
  const int t = threadIdx.x;
  __shared__ int sc[256];
  int kept[4];
  int c = 0;
#pragma unroll
  for (int k = 0; k < 4; ++k) {
    const int j = t * 4 + k;
    const int kp = (j == 0) ? 1 : (mask[b * (SEQ - 1) + j - 1] != 0);
    kept[k] = kp;
    c += kp;
  }
  sc[t] = c;
  __syncthreads();
  for (int off = 1; off < 256; off <<= 1) {
    const int v = (t >= off) ? sc[t - off] : 0;
    __syncthreads();
    sc[t] += v;
    __syncthreads();
  }
  int pos = sc[t] - c;          // exclusive prefix
  const int total = sc[255];
#pragma unroll
  for (int k = 0; k < 4; ++k) {
    const int j = t * 4 + k;
    inv[b * SEQ + j] = kept[k] ? pos : -1;
    pos += kept[k];
  }
  if (t == 0) nkeep[b] = total;
}

// ---------------- Kernel A: x f32 -> bf16 -----------------------------------
__global__ __launch_bounds__(256) void cvt_x(
    const float* __restrict__ in, unsigned short* __restrict__ out) {
  const int i = (blockIdx.x * 256 + threadIdx.x) * 4;
  const float4 v = *reinterpret_cast<const float4*>(in + i);
  short4 o;
  o.x = (short)f2bf(v.x);
  o.y = (short)f2bf(v.y);
  o.z = (short)f2bf(v.z);
  o.w = (short)f2bf(v.w);
  *reinterpret_cast<short4*>(out + i) = o;
}

// ---------------- Kernel 0: w f32 [1024][3072] -> wT bf16 [3072][1024] ------
__global__ __launch_bounds__(256) void transpose_w(
    const float* __restrict__ w, unsigned short* __restrict__ wT) {
  __shared__ unsigned short t[64][68];
  const int tid = threadIdx.x;
  const int bk = blockIdx.x;
  const int bn = blockIdx.y;
  const int r = tid >> 4;
  const int c = (tid & 15) * 4;
#pragma unroll
  for (int rr = 0; rr < 64; rr += 16) {
    const float4 v = *reinterpret_cast<const float4*>(
        w + (size_t)(bk * 64 + r + rr) * 3072 + bn * 64 + c);
    t[r + rr][c + 0] = f2bf(v.x);
    t[r + rr][c + 1] = f2bf(v.y);
    t[r + rr][c + 2] = f2bf(v.z);
    t[r + rr][c + 3] = f2bf(v.w);
  }
  __syncthreads();
#pragma unroll
  for (int rr = 0; rr < 64; rr += 16) {
    short4 o;
    o.x = (short)t[c + 0][r + rr];
    o.y = (short)t[c + 1][r + rr];
    o.z = (short)t[c + 2][r + rr];
    o.w = (short)t[c + 3][r + rr];
    *reinterpret_cast<short4*>(
        wT + (size_t)(bn * 64 + r + rr) * 1024 + bk * 64 + c) = o;
  }
}

// ---------------- Kernel 1: qkv = x @ w -------------------------------------
// Qh: [b,h,n,64] PRE-SCALED by 0.125*log2e ; Kc,Vc: [b,h,i,64] compacted rows.
// Epilogue: per-wave LDS bounce (reusing Al/Bl after a barrier) -> bf16x8
// 16B coalesced stores (one instr = 8 rows x 128B dense). V is row-major;
// a separate transpose_v kernel produces Vtc.
// Grid: dim3(64,24) NATURAL order — measured L2-optimal (round-5 swizzle
// experiment: remap quadrupled FETCH_SIZE). Do not swizzle.
__global__ __launch_bounds__(256) void qkv_gemm(
    const unsigned short* __restrict__ x, const unsigned short* __restrict__ wT,
    const int* __restrict__ inv,
    unsigned short* __restrict__ Qh, unsigned short* __restrict__ Kc,
    unsigned short* __restrict__ Vc) {
  __shared__ unsigned short Al[128 * 32];
  __shared__ unsigned short Bl[128 * 32];
  const int tid = threadIdx.x;
  const int lane = tid & 63;
  const int wave = tid >> 6;
  const int m0 = blockIdx.x * 128;       // 64 M-tiles
  const int n0 = blockIdx.y * 128;       // 24 N-tiles
  const int wm = (wave >> 1) * 64;
  const int wn = (wave & 1) * 64;
  const int l15 = lane & 15;
  const int kb8 = (lane >> 4) * 8;
  const int lg4 = (lane >> 4) * 4;

  f32x4 acc[4][4] = {};

  for (int kt = 0; kt < DIM; kt += 32) {
    __syncthreads();
#pragma unroll
    for (int rnd = 0; rnd < 2; ++rnd) {
      const int off = tid * 16 + rnd * 4096;
      const int row = off >> 6;
      const int kc = (off & 63) >> 1;
      gload_lds16(x + (size_t)(m0 + row) * DIM + kt + kc, (char*)Al + off);
      gload_lds16(wT + (size_t)(n0 + row) * DIM + kt + kc, (char*)Bl + off);
    }
    __syncthreads();
    bf16x8 af[4], bfr[4];
#pragma unroll
    for (int i = 0; i < 4; ++i)
      af[i] = *reinterpret_cast<const bf16x8*>(&Al[(wm + i * 16 + l15) * 32 + kb8]);
#pragma unroll
    for (int j = 0; j < 4; ++j)
      bfr[j] = *reinterpret_cast<const bf16x8*>(&Bl[(wn + j * 16 + l15) * 32 + kb8]);
#pragma unroll
    for (int i = 0; i < 4; ++i)
#pragma unroll
      for (int j = 0; j < 4; ++j)
        acc[i][j] = __builtin_amdgcn_mfma_f32_16x16x32_bf16(af[i], bfr[j], acc[i][j], 0, 0, 0);
  }

  // ---- epilogue: LDS bounce -> 16B coalesced stores ----
  __syncthreads();   // all waves done reading Al/Bl
  // per-wave scratch: 16 rows x 72 shorts (144B row stride, 16B-aligned)
  unsigned short* Sw = (wave < 2 ? Al : Bl) + (wave & 1) * (16 * 72);
  const int sec = n0 >> 10;              // block-uniform: 0=q 1=k 2=v
  const float sc = (sec == 0) ? QSCALE_L2 : 1.0f;
  const int h = ((n0 + wn) >> 6) & 15;   // wave-uniform head
#pragma unroll
  for (int i = 0; i < 4; ++i) {
    // write phase: C-layout (row=lg4+r, col=j*16+l15) -> Sw[16][72]
#pragma unroll
    for (int j = 0; j < 4; ++j)
#pragma unroll
      for (int r = 0; r < 4; ++r)
        Sw[(lg4 + r) * 72 + j * 16 + l15] = f2bf(acc[i][j][r] * sc);
    // read phase: lane -> (row = pass*8 + lane>>3, 16B chunk = lane&7)
    // (same-wave DS ops are ordered; no barrier needed between phases)
#pragma unroll
    for (int pass = 0; pass < 2; ++pass) {
      const int row = pass * 8 + (lane >> 3);
      const int chunk = lane & 7;
      const bf16x8 vv = *reinterpret_cast<const bf16x8*>(&Sw[row * 72 + chunk * 8]);
      const int grow = m0 + wm + i * 16 + row;
      const int b = grow >> 10;
      const int n = grow & 1023;
      const size_t bh = (size_t)b * HEADS + h;
      if (sec == 0) {
        *reinterpret_cast<bf16x8*>(&Qh[(bh * SEQ + n) * DH + chunk * 8]) = vv;
      } else {
        const int iv = inv[b * SEQ + n];
        if (iv >= 0) {
          if (sec == 1)
            *reinterpret_cast<bf16x8*>(&Kc[(bh * SEQ + iv) * DH + chunk * 8]) = vv;
          else
            *reinterpret_cast<bf16x8*>(&Vc[(bh * SEQ + iv) * DH + chunk * 8]) = vv;
        }
      }
    }
  }
}

// ---------------- Kernel 1b: Vc [bh][i][64] -> Vtc [bh][64][i] --------------
__global__ __launch_bounds__(256) void transpose_v(
    const unsigned short* __restrict__ Vc, unsigned short* __restrict__ Vtc) {
  __shared__ unsigned short t[64][72];
  const int tid = threadIdx.x;
  const int i0 = blockIdx.x * 64;
  const int bhi = blockIdx.y;            // 0..127
  const unsigned short* src = Vc + (size_t)bhi * SEQ * DH;
  unsigned short* dst = Vtc + (size_t)bhi * DH * SEQ;
  const int r = tid >> 3;        // 0..31
  const int c = (tid & 7) * 8;   // 0..56
#pragma unroll
  for (int rr = 0; rr < 64; rr += 32) {
    const bf16x8 v = *reinterpret_cast<const bf16x8*>(
        src + (size_t)(i0 + r + rr) * DH + c);
    *reinterpret_cast<bf16x8*>(&t[r + rr][c]) = v;
  }
  __syncthreads();
#pragma unroll
  for (int dd = 0; dd < 64; dd += 32) {
    const int d = r + dd;
    bf16x8 o;
#pragma unroll
    for (int e = 0; e < 8; ++e) o[e] = (short)t[c + e][d];
    *reinterpret_cast<bf16x8*>(dst + (size_t)d * SEQ + i0 + c) = o;
  }
}

// ---------------- Kernel 2: flash attention over compacted KV ---------------
// block = 4 waves x 32 q-rows of one (b,h); 32x32x16 MFMA.
// K and V staged in double-buffered LDS via global_load_lds (one copy/block).
// XOR chunk-swizzle on the GLOBAL source + ds_read address (rule #21).
// Mask pen is tail-tile-only and computed in registers (kv < nk).
__global__ __launch_bounds__(256) void attn_fwd5(
    const unsigned short* __restrict__ Qh, const unsigned short* __restrict__ Kc,
    const unsigned short* __restrict__ Vtc,
    const int* __restrict__ nkeep, float* __restrict__ out) {
  __shared__ alignas(16) unsigned char Kl[2][8192];
  __shared__ alignas(16) unsigned char Vl[2][8192];
  __shared__ float corrw[4][32];
  const int tid = threadIdx.x;
  const int lane = tid & 63;
  const int wave = tid >> 6;
  const int l31 = lane & 31;
  const int hi = lane >> 5;
  const int h8 = hi * 8;
  const bool islo = lane < 32;

  // XCD swizzle: 128 consecutive logical blocks (16 heads) per XCD
  const int bid = ((blockIdx.x & 7) << 7) | (blockIdx.x >> 3);
  const int b = bid >> 7;
  const int hh = (bid >> 3) & 15;
  const int qc = bid & 7;
  const size_t bh = (size_t)b * HEADS + hh;
  const int q0 = qc * 128 + wave * 32;

  const int nk = nkeep[b];
  const int ntile = (nk + 63) >> 6;

  const unsigned short* Q = Qh + bh * SEQ * DH;
  const unsigned short* K = Kc + bh * SEQ * DH;
  const unsigned short* V = Vtc + bh * DH * SEQ;   // [64][1024] compacted cols

  auto STAGE = [&](int buf, int kt) {
#pragma unroll
    for (int p = 0; p < 2; ++p) {
      const int off = p * 4096 + tid * 16;
      const int row = off >> 7;
      const int chunk = (off >> 4) & 7;
      const int sch = chunk ^ (row & 7);
      gload_lds16(K + (size_t)(kt + row) * DH + sch * 8, &Kl[buf][off]);
      gload_lds16(V + (size_t)row * SEQ + kt + sch * 8, &Vl[buf][off]);
    }
  };

  STAGE(0, 0);

  bf16x8 qf[4];
#pragma unroll
  for (int ds = 0; ds < 4; ++ds)
    qf[ds] = *reinterpret_cast<const bf16x8*>(
        Q + (size_t)(q0 + l31) * DH + ds * 16 + h8);

  u32x4 onesu = {0u, 0u, 0u, 0u};
  onesu.x = islo ? 0x3F80u : 0u;     // bf16 1.0 at k==0 of lane-half 0
  const bf16x8 onesf = __builtin_bit_cast(bf16x8, onesu);

  f32x16 Od0 = (f32x16)0.f, Od1 = (f32x16)0.f;
  float m_ = 0.f, l_ = 0.f;

  __syncthreads();   // drains prologue STAGE

  int cur = 0;
  for (int ti = 0; ti < ntile; ++ti) {
    const int kt = ti * 64;
    if (ti + 1 < ntile) STAGE(cur ^ 1, kt + 64);

    // ---- S^T = K·Q^T from LDS (swizzled ds_read_b128) ----
    f32x16 st0 = (f32x16)0.f, st1 = (f32x16)0.f;
    __builtin_amdgcn_s_setprio(1);
#pragma unroll
    for (int ds = 0; ds < 4; ++ds) {
      const int c0 = (ds * 2 + hi) ^ (l31 & 7);
      const bf16x8 kf0 = *reinterpret_cast<const bf16x8*>(
          &Kl[cur][l31 * 128 + c0 * 16]);
      st0 = __builtin_amdgcn_mfma_f32_32x32x16_bf16(kf0, qf[ds], st0, 0, 0, 0);
      const bf16x8 kf1 = *reinterpret_cast<const bf16x8*>(
          &Kl[cur][(32 + l31) * 128 + c0 * 16]);
      st1 = __builtin_amdgcn_mfma_f32_32x32x16_bf16(kf1, qf[ds], st1, 0, 0, 0);
    }
    __builtin_amdgcn_s_setprio(0);

    // tail-only mask via rank-1 MFMA: st[kv][q] += pen[kv], pen = (kv<nk)?0:-1e4*log2e
    if (ti == ntile - 1) {
      const unsigned short pv = f2bf(PEN_L2);
      const unsigned short pu0 = (kt + l31 < nk) ? (unsigned short)0 : pv;
      const unsigned short pu1 = (kt + 32 + l31 < nk) ? (unsigned short)0 : pv;
      u32x4 p0 = {0u, 0u, 0u, 0u}, p1 = {0u, 0u, 0u, 0u};
      p0.x = islo ? (unsigned)pu0 : 0u;
      p1.x = islo ? (unsigned)pu1 : 0u;
      st0 = __builtin_amdgcn_mfma_f32_32x32x16_bf16(
          __builtin_bit_cast(bf16x8, p0), onesf, st0, 0, 0, 0);
      st1 = __builtin_amdgcn_mfma_f32_32x32x16_bf16(
          __builtin_bit_cast(bf16x8, p1), onesf, st1, 0, 0, 0);
    }
    // row max
    float a[8];
#pragma unroll
    for (int i = 0; i < 8; ++i)
      a[i] = fmaxf(fmaxf(st0[i], st0[i + 8]), fmaxf(st1[i], st1[i + 8]));
#pragma unroll
    for (int k = 4; k >= 1; k >>= 1)
#pragma unroll
      for (int i = 0; i < k; ++i) a[i] = fmaxf(a[i], a[i + k]);
    const float mx = fmaxf(a[0], __shfl_xor(a[0], 32));
    // deferred rescale (rare)
    if (!__all(mx <= m_ + THR_L2)) {
      const float mn = fmaxf(m_, mx);
      const float corr = fexp2(m_ - mn);
      m_ = mn;
      l_ *= corr;
      if (islo) corrw[wave][l31] = corr;
      f32x4 cv[4];
#pragma unroll
      for (int j = 0; j < 4; ++j)
        cv[j] = *reinterpret_cast<const f32x4*>(&corrw[wave][j * 8 + (h8 >> 1)]);
#pragma unroll
      for (int r = 0; r < 16; ++r) {
        Od0[r] *= cv[r >> 2][r & 3];
        Od1[r] *= cv[r >> 2][r & 3];
      }
    }
    // P = exp2(st - m)
#pragma unroll
    for (int i = 0; i < 16; ++i) {
      st0[i] = fexp2(st0[i] - m_);
      st1[i] = fexp2(st1[i] - m_);
    }
    // row sum
    float s8[8];
#pragma unroll
    for (int i = 0; i < 8; ++i)
      s8[i] = (st0[i] + st0[i + 8]) + (st1[i] + st1[i + 8]);
#pragma unroll
    for (int k = 4; k >= 1; k >>= 1)
#pragma unroll
      for (int i = 0; i < k; ++i) s8[i] += s8[i + k];
    l_ += s8[0] + __shfl_xor(s8[0], 32);
    // pack P -> A-frags (cvt_pk + permlane32_swap)
    bf16x8 pf[4];
#pragma unroll
    for (int t = 0; t < 2; ++t) {
#pragma unroll
      for (int bq = 0; bq < 2; ++bq) {
        const int o = 8 * bq;
        float e0 = t ? st1[o + 0] : st0[o + 0], e1 = t ? st1[o + 1] : st0[o + 1];
        float e2 = t ? st1[o + 2] : st0[o + 2], e3 = t ? st1[o + 3] : st0[o + 3];
        float e4 = t ? st1[o + 4] : st0[o + 4], e5 = t ? st1[o + 5] : st0[o + 5];
        float e6 = t ? st1[o + 6] : st0[o + 6], e7 = t ? st1[o + 7] : st0[o + 7];
        unsigned A0, A1, B0, B1;
        asm("v_cvt_pk_bf16_f32 %0, %1, %2" : "=v"(A0) : "v"(e0), "v"(e1));
        asm("v_cvt_pk_bf16_f32 %0, %1, %2" : "=v"(A1) : "v"(e2), "v"(e3));
        asm("v_cvt_pk_bf16_f32 %0, %1, %2" : "=v"(B0) : "v"(e4), "v"(e5));
        asm("v_cvt_pk_bf16_f32 %0, %1, %2" : "=v"(B1) : "v"(e6), "v"(e7));
        asm("v_permlane32_swap_b32 %0, %1\n\ts_nop 1" : "+v"(A0), "+v"(B0));
        asm("v_permlane32_swap_b32 %0, %1\n\ts_nop 1" : "+v"(A1), "+v"(B1));
        u32x4 pk4;
        pk4.x = A0; pk4.y = A1; pk4.z = B0; pk4.w = B1;
        pf[t * 2 + bq] = __builtin_bit_cast(bf16x8, pk4);
      }
    }
    // ---- PV from LDS V tile (swizzled ds_read_b128) ----
    __builtin_amdgcn_s_setprio(1);
#pragma unroll
    for (int kvs = 0; kvs < 4; ++kvs) {
      const int c0 = (kvs * 2 + hi) ^ (l31 & 7);
      const bf16x8 v0 = *reinterpret_cast<const bf16x8*>(
          &Vl[cur][l31 * 128 + c0 * 16]);
      Od0 = __builtin_amdgcn_mfma_f32_32x32x16_bf16(pf[kvs], v0, Od0, 0, 0, 0);
      const bf16x8 v1 = *reinterpret_cast<const bf16x8*>(
          &Vl[cur][(32 + l31) * 128 + c0 * 16]);
      Od1 = __builtin_amdgcn_mfma_f32_32x32x16_bf16(pf[kvs], v1, Od1, 0, 0, 0);
    }
    __builtin_amdgcn_s_setprio(0);

    __syncthreads();
    cur ^= 1;
  }

  // epilogue: O / l
  if (islo) corrw[wave][l31] = 1.0f / l_;
  f32x4 lv[4];
#pragma unroll
  for (int j = 0; j < 4; ++j)
    lv[j] = *reinterpret_cast<const f32x4*>(&corrw[wave][j * 8 + (h8 >> 1)]);
#pragma unroll
  for (int r = 0; r < 16; ++r) {
    const int q = q0 + (r & 3) + 8 * (r >> 2) + (hi << 2);
    out[((size_t)b * SEQ + q) * (HEADS * DH) + hh * DH + 0 * 32 + l31] =
        Od0[r] * lv[r >> 2][r & 3];
    out[((size_t)b * SEQ + q) * (HEADS * DH) + hh * DH + 1 * 32 + l31] =
        Od1[r] * lv[r >> 2][r & 3];
  }
}

// ---------------- launch ----------------------------------------------------
extern "C" void kernel_launch(void* const* d_in, const int* in_sizes, int n_in,
                              void* d_out, int out_size, void* d_ws, size_t ws_size,
                              hipStream_t stream) {
  const float* x = (const float*)d_in[0];
  const int* mask = (const int*)d_in[1];
  const float* w = (const float*)d_in[2];
  float* outp = (float*)d_out;

  char* ws = (char*)d_ws;
  unsigned short* xb   = (unsigned short*)(ws);                  // 16777216 B
  unsigned short* wT   = (unsigned short*)(ws + 16777216);       //  6291456 B
  unsigned short* Qh   = (unsigned short*)(ws + 23068672);       // 16777216 B
  unsigned short* Kc   = (unsigned short*)(ws + 39845888);       // 16777216 B
  unsigned short* Vc   = (unsigned short*)(ws + 56623104);       // 16777216 B
  int*            inv  = (int*)(ws + 73400320);                  //    32768 B
  int*            nkp  = (int*)(ws + 73433088);                  //       32 B
  // Vtc reuses the xb region: xb is dead after qkv_gemm.
  unsigned short* Vtc  = xb;

  build_keep<<<dim3(8), 256, 0, stream>>>(mask, inv, nkp);
  cvt_x<<<dim3(8192), 256, 0, stream>>>(x, xb);
  transpose_w<<<dim3(16, 48), 256, 0, stream>>>(w, wT);
  qkv_gemm<<<dim3(64, 24), 256, 0, stream>>>(xb, wT, inv, Qh, Kc, Vc);
  transpose_v<<<dim3(16, 128), 256, 0, stream>>>(Vc, Vtc);
  attn_fwd5<<<dim3(1024), 256, 0, stream>>>(Qh, Kc, Vtc, nkp, outp);
}